// Round 5
// baseline (438.463 us; speedup 1.0000x reference)
//
#include <hip/hip_runtime.h>
#include <hip/hip_bf16.h>
#include <cstdint>
#include <cstddef>

// Problem constants (from reference)
#define NSRC   200000
#define NF     128
#define NHID   1500
#define NHIDP  1536     // padded hidden dim (multiple of 128)
#define NCLS   64
#define E0N    1600000
#define E1N    500000
#define RES0   50000
#define RES1   10000

// CSR bucket-sort parameters
#define CH     4096                       // edges per chunk
#define NCH0   ((E0N + CH - 1) / CH)      // 391
#define NCH1   ((E1N + CH - 1) / CH)      // 123
#define NB0    ((RES0 + 255) / 256)      // 196 buckets of 256 targets
#define NB1    ((RES1 + 255) / 256)      // 40

#define PREP_BLOCKS  ((256 * NHIDP + 128 * NHIDP + NHIDP + 255) / 256)   // 2310
#define COPYX_BLOCKS ((NSRC * NF) / (256 * 8))                           // 12500

typedef __bf16 bf16x8 __attribute__((ext_vector_type(8)));
typedef float  f32x4  __attribute__((ext_vector_type(4)));
typedef unsigned short u16x8 __attribute__((ext_vector_type(8)));
typedef unsigned int u32;
typedef unsigned long long u64;

__device__ __forceinline__ unsigned short f2bf(float f) {
    union { float f; unsigned u; } v; v.f = f;
    unsigned r = v.u + 0x7fffu + ((v.u >> 16) & 1u);   // RNE
    return (unsigned short)(r >> 16);
}
__device__ __forceinline__ float bf2f(unsigned short b) {
    union { u32 u; float f; } v; v.u = ((u32)b) << 16;
    return v.f;
}

// pack 2 f32 -> 2 bf16 in one u32, inline asm (no builtin on gfx950)
__device__ __forceinline__ u32 cvt_pk_bf16(float lo, float hi) {
    u32 r;
    asm("v_cvt_pk_bf16_f32 %0, %1, %2" : "=v"(r) : "v"(lo), "v"(hi));
    return r;
}

// async 16B global -> LDS DMA (dest = wave-uniform lds base + lane*16)
__device__ __forceinline__ void lds_dma16(const void* g, void* lds) {
    __builtin_amdgcn_global_load_lds(
        (const __attribute__((address_space(1))) unsigned int*)g,
        (__attribute__((address_space(3))) unsigned int*)lds, 16, 0, 0);
}

// raw barrier/wait primitives: s_barrier WITHOUT the compiler's vmcnt(0) drain.
__device__ __forceinline__ void raw_barrier() {
    __asm__ volatile("s_barrier" ::: "memory");
}
__device__ __forceinline__ void wait_vm4() {
    __asm__ volatile("s_waitcnt vmcnt(4)" ::: "memory");
}
__device__ __forceinline__ void wait_vm0() {
    __asm__ volatile("s_waitcnt vmcnt(0)" ::: "memory");
}

// ---------------- setup: weight prep + x->bf16 copy (merged) -----------------
// W2f layout (MFMA-fragment order): for output col n, k = j*128 + kk*32 +
// hi*16 + qd*4 + e  ->  W2f[((j*4+kk)*128 + n)*32 + qd*8 + hi*4 + e].
// Layer-2 B-frag (n-frag, kk, quad) is then ONE contiguous 16B load.
__global__ __launch_bounds__(256) void setup_kernel(
        const float* __restrict__ x, unsigned short* __restrict__ xbf,
        const float* __restrict__ W1r, const float* __restrict__ W1n,
        const float* __restrict__ b1,
        const float* __restrict__ W2r, const float* __restrict__ W2n,
        unsigned short* __restrict__ WcatT, unsigned short* __restrict__ W2f,
        float* __restrict__ b1e) {
    int bid = blockIdx.x;
    if (bid < PREP_BLOCKS) {
        int id = bid * 256 + threadIdx.x;
        if (id < 256 * NHIDP) {
            int n = id >> 8, k = id & 255;
            float v = 0.f;
            if (n < NHID) v = (k < NF) ? W1r[k * NHID + n] : W1n[(k - NF) * NHID + n];
            WcatT[n * 256 + k] = f2bf(v);
        } else {
            int id2 = id - 256 * NHIDP;
            if (id2 < 128 * NHIDP) {
                int n = id2 / NHIDP, k = id2 % NHIDP;
                float v = 0.f;
                if (k < NHID) v = (n < 64) ? W2n[k * 64 + n] : W2r[k * 64 + (n - 64)];
                int j = k >> 7, w = k & 127;
                int kk = w >> 5, r = w & 31;
                int hi = r >> 4, qd = (r >> 2) & 3, e = r & 3;
                W2f[(((size_t)(j * 4 + kk) * 128 + n) * 32) + qd * 8 + hi * 4 + e] = f2bf(v);
            } else {
                int c = id2 - 128 * NHIDP;
                if (c < NHIDP) b1e[c] = (c < NHID) ? b1[c] : 0.f;
            }
        }
    } else {
        size_t i = ((size_t)(bid - PREP_BLOCKS) * 256 + threadIdx.x) * 8;
        const float4* s = (const float4*)(x + i);
        float4 a = s[0], b = s[1];
        u16x8 o;
        o[0] = f2bf(a.x); o[1] = f2bf(a.y); o[2] = f2bf(a.z); o[3] = f2bf(a.w);
        o[4] = f2bf(b.x); o[5] = f2bf(b.y); o[6] = f2bf(b.z); o[7] = f2bf(b.w);
        *(u16x8*)(xbf + i) = o;
    }
}

// ---------------- CSR phase 1a: per-chunk bucket histogram (both graphs) -----
__device__ __forceinline__ void p1a_body(const int* __restrict__ tgt, int n,
                                         int nb, u32* __restrict__ H, int c) {
    __shared__ u32 lhist[256];
    int tid = threadIdx.x;
    lhist[tid] = 0;
    __syncthreads();
#pragma unroll
    for (int it = 0; it < CH / 256; ++it) {
        int i = c * CH + it * 256 + tid;
        if (i < n) atomicAdd(&lhist[((u32)tgt[i]) >> 8], 1u);
    }
    __syncthreads();
    if (tid < nb) H[c * nb + tid] = lhist[tid];
}

__global__ __launch_bounds__(256) void p1a_both_kernel(
        const int* __restrict__ t0, const int* __restrict__ t1,
        u32* __restrict__ H1, u32* __restrict__ H2) {
    int b = blockIdx.x;
    if (b < NCH0) p1a_body(t0, E0N, NB0, H1, b);
    else          p1a_body(t1, E1N, NB1, H2, b - NCH0);
}

// ---------------- bscan: per-bucket exclusive scan over chunks + totals ------
__device__ __forceinline__ void bscan_body(const u32* __restrict__ H,
                                           int nch, int nb, int b,
                                           u32* __restrict__ base_rel,
                                           u32* __restrict__ Bsum) {
    __shared__ u32 part[512];
    int t = threadIdx.x;
    part[t] = (t < nch) ? H[t * nb + b] : 0u;
    __syncthreads();
    for (int d = 1; d < 512; d <<= 1) {
        u32 v = part[t];
        u32 add = (t >= d) ? part[t - d] : 0u;
        __syncthreads();
        part[t] = v + add;
        __syncthreads();
    }
    if (t < nch) base_rel[t * nb + b] = (t == 0) ? 0u : part[t - 1];
    if (t == 0) Bsum[b] = part[nch - 1];
}

__global__ __launch_bounds__(512) void bscan_both_kernel(
        const u32* __restrict__ H1, u32* __restrict__ base1, u32* __restrict__ Bsum1,
        const u32* __restrict__ H2, u32* __restrict__ base2, u32* __restrict__ Bsum2) {
    int b = blockIdx.x;
    if (b < NB0) bscan_body(H1, NCH0, NB0, b, base1, Bsum1);
    else         bscan_body(H2, NCH1, NB1, b - NB0, base2, Bsum2);
}

// ---------------- boff: exclusive scan over bucket totals (both graphs) ------
__global__ __launch_bounds__(256) void boff_kernel(const u32* __restrict__ Bsum1,
                                                   u32* __restrict__ boff1, int nb1,
                                                   const u32* __restrict__ Bsum2,
                                                   u32* __restrict__ boff2, int nb2) {
    const u32* B = blockIdx.x ? Bsum2 : Bsum1;
    u32* O = blockIdx.x ? boff2 : boff1;
    int nb = blockIdx.x ? nb2 : nb1;
    __shared__ u32 part[256];
    int t = threadIdx.x;
    part[t] = (t < nb) ? B[t] : 0u;
    __syncthreads();
    for (int d = 1; d < 256; d <<= 1) {
        u32 v = part[t];
        u32 add = (t >= d) ? part[t - d] : 0u;
        __syncthreads();
        part[t] = v + add;
        __syncthreads();
    }
    if (t < nb) O[t] = (t == 0) ? 0u : part[t - 1];
}

// ---------------- phase 1b: bucket-grouped scatter of (tgt,src) pairs --------
__device__ __forceinline__ void p1b_body(const int* __restrict__ src,
                                         const int* __restrict__ tgt, int n,
                                         int nb, const u32* __restrict__ base_rel,
                                         const u32* __restrict__ boff,
                                         u64* __restrict__ bucketed, int c) {
    __shared__ u32 lcur[256];
    __shared__ u32 lbase[256];
    int tid = threadIdx.x;
    lcur[tid] = 0;
    if (tid < nb) lbase[tid] = base_rel[c * nb + tid] + boff[tid];
    __syncthreads();
#pragma unroll
    for (int it = 0; it < CH / 256; ++it) {
        int i = c * CH + it * 256 + tid;
        if (i < n) {
            u32 t = (u32)tgt[i];
            u32 s = (u32)src[i];
            u32 b = t >> 8;
            u32 r = atomicAdd(&lcur[b], 1u);
            bucketed[lbase[b] + r] = ((u64)t << 32) | (u64)s;
        }
    }
}

__global__ __launch_bounds__(256) void p1b_both_kernel(
        const int* __restrict__ s0, const int* __restrict__ t0,
        const u32* __restrict__ base1, const u32* __restrict__ boff1,
        u64* __restrict__ bkt1,
        const int* __restrict__ s1, const int* __restrict__ t1,
        const u32* __restrict__ base2, const u32* __restrict__ boff2,
        u64* __restrict__ bkt2) {
    int b = blockIdx.x;
    if (b < NCH0) p1b_body(s0, t0, E0N, NB0, base1, boff1, bkt1, b);
    else          p1b_body(s1, t1, E1N, NB1, base2, boff2, bkt2, b - NCH0);
}

// ---------------- phase 2: per-bucket sort -> CSR + per-target off/cnt -------
__device__ __forceinline__ void p2_body(const u64* __restrict__ bucketed,
                                        const u32* __restrict__ boff,
                                        int nb, int res, int etot,
                                        int* __restrict__ csr,
                                        u32* __restrict__ off_out,
                                        u32* __restrict__ cnt_out, int b) {
    __shared__ u32 lhist[256];
    __shared__ u32 part[256];
    __shared__ u32 cur[256];
    int tid = threadIdx.x;
    u32 start = boff[b];
    u32 end = (b == nb - 1) ? (u32)etot : boff[b + 1];
    u32 count = end - start;
    if (tid < 256) lhist[tid] = 0;
    __syncthreads();
    for (u32 i = tid; i < count; i += 1024) {
        u32 t = (u32)(bucketed[start + i] >> 32);
        atomicAdd(&lhist[t & 255u], 1u);
    }
    __syncthreads();
    if (tid < 256) part[tid] = lhist[tid];
    __syncthreads();
    for (int d = 1; d < 256; d <<= 1) {
        u32 v = (tid < 256) ? part[tid] : 0u;
        u32 add = (tid >= d && tid < 256) ? part[tid - d] : 0u;
        __syncthreads();
        if (tid < 256) part[tid] = v + add;
        __syncthreads();
    }
    if (tid < 256) {
        u32 excl = (tid == 0) ? 0u : part[tid - 1];
        cur[tid] = excl;
        int tg = (b << 8) + tid;
        if (tg < res) {
            off_out[tg] = start + excl;
            cnt_out[tg] = lhist[tid];
        }
    }
    __syncthreads();
    for (u32 i = tid; i < count; i += 1024) {
        u64 pr = bucketed[start + i];
        u32 lt = ((u32)(pr >> 32)) & 255u;
        u32 r = atomicAdd(&cur[lt], 1u);
        csr[start + r] = (int)(u32)pr;
    }
}

__global__ __launch_bounds__(1024) void p2_both_kernel(
        const u64* __restrict__ bkt1, const u32* __restrict__ boff1,
        int* __restrict__ csr1, u32* __restrict__ off1, u32* __restrict__ cnt1,
        const u64* __restrict__ bkt2, const u32* __restrict__ boff2,
        int* __restrict__ csr2, u32* __restrict__ off2, u32* __restrict__ cnt2) {
    int b = blockIdx.x;
    if (b < NB0) p2_body(bkt1, boff1, NB0, RES0, E0N, csr1, off1, cnt1, b);
    else         p2_body(bkt2, boff2, NB1, RES1, E1N, csr2, off2, cnt2, b - NB0);
}

// ---------------- layer-1 mean: 1 wave/row, 16 lanes/row, 4 edges/instr ------
__global__ __launch_bounds__(256) void agg1_csr_kernel(
        const unsigned short* __restrict__ xbf, const int* __restrict__ csr,
        const u32* __restrict__ off, const u32* __restrict__ cnt,
        unsigned short* __restrict__ mean1) {
    int row = blockIdx.x * 4 + (threadIdx.x >> 6);
    int lane = threadIdx.x & 63;
    if (row >= RES0) return;
    int q = lane >> 4, c16 = lane & 15;            // edge slot, 16B chunk
    u32 base = off[row], deg = cnt[row];
    float acc[8] = {};
    u32 e = 0;
    // 8 edges in flight (2 gathers/iter)
    for (; e + 8 <= deg; e += 8) {
        int s0 = csr[base + e + q];
        int s1 = csr[base + e + 4 + q];
        u16x8 v0 = *(const u16x8*)(xbf + (size_t)s0 * NF + c16 * 8);
        u16x8 v1 = *(const u16x8*)(xbf + (size_t)s1 * NF + c16 * 8);
#pragma unroll
        for (int i = 0; i < 8; ++i) acc[i] += bf2f(v0[i]) + bf2f(v1[i]);
    }
    for (; e + 4 <= deg; e += 4) {
        int s0 = csr[base + e + q];
        u16x8 v0 = *(const u16x8*)(xbf + (size_t)s0 * NF + c16 * 8);
#pragma unroll
        for (int i = 0; i < 8; ++i) acc[i] += bf2f(v0[i]);
    }
    if (e < deg) {
        bool valid = (e + q) < deg;
        int s0 = csr[base + (valid ? e + q : e)];
        u16x8 v0 = *(const u16x8*)(xbf + (size_t)s0 * NF + c16 * 8);
        if (valid) {
#pragma unroll
            for (int i = 0; i < 8; ++i) acc[i] += bf2f(v0[i]);
        }
    }
    // reduce across the 4 edge slots (lane bits 4,5)
#pragma unroll
    for (int i = 0; i < 8; ++i) {
        acc[i] += __shfl_xor(acc[i], 32, 64);
        acc[i] += __shfl_xor(acc[i], 16, 64);
    }
    if (q == 0) {
        float inv = 1.0f / fmaxf((float)deg, 1.0f);
        u16x8 o;
#pragma unroll
        for (int i = 0; i < 8; ++i) o[i] = f2bf(acc[i] * inv);
        *(u16x8*)(mean1 + (size_t)row * NF + c16 * 8) = o;
    }
}

// ---------------- fused GEMM staging helper (XOR-swizzled source) ------------
// LDS layout [row][32 shorts]; 16B chunk q of row n holds SOURCE chunk
// q ^ (n&3)  (pre-swizzled global address, linear DMA dest — rule #21).
__device__ __forceinline__ void stage_chunk(
        const unsigned short* __restrict__ xbf, const unsigned short* __restrict__ mean1,
        const unsigned short* __restrict__ WcatT, int m0, int j, int kt,
        unsigned short* As, unsigned short* Bs, int wid, int lane) {
    int ksel = kt * 32;
    const unsigned short* srcA = (ksel < 128)
        ? xbf + (size_t)m0 * NF + ksel
        : mean1 + (size_t)m0 * NF + (ksel - 128);
#pragma unroll
    for (int ci = 0; ci < 2; ++ci) {
        int cb = ci * 256 + wid * 64;
        int chunk = cb + lane;
        int n = chunk >> 2, kc = (chunk & 3) ^ (n & 3);
        lds_dma16(srcA + (size_t)n * NF + kc * 8, &As[cb * 8]);
    }
    const unsigned short* srcB = WcatT + (size_t)(j * 128) * 256 + ksel;
#pragma unroll
    for (int ci = 0; ci < 2; ++ci) {
        int cb = ci * 256 + wid * 64;
        int chunk = cb + lane;
        int n = chunk >> 2, kc = (chunk & 3) ^ (n & 3);
        lds_dma16(srcB + (size_t)n * 256 + kc * 8, &Bs[cb * 8]);
    }
}

// ---------------- fused GEMM v5: wm-only waves, in-register layer-2 ----------
// 128-row tile, 4 waves, wave = 32 rows x FULL 128 cols (a[2] x b[8], 16
// MFMA/phase — proven fatness). Each wave owns complete k for its rows:
// layer-2 runs fully in registers (R3-verified hacc->a2w slot->k mapping,
// kk 0..3), pacc[2][8] accumulates the complete output over all 12 j-blocks,
// epilogue writes pnbf/root64 directly. No Ht, no second barrier, no
// cross-wave reduction. W2f fragment layout -> one 16B load per B-frag.
// LDS 48 KB. As/Bs XOR-swizzled (2-way bank aliasing, free).
__global__ __launch_bounds__(256, 2) void fused_gemm_kernel(
        const unsigned short* __restrict__ xbf, const unsigned short* __restrict__ mean1,
        const unsigned short* __restrict__ WcatT, const float* __restrict__ b1e,
        const unsigned short* __restrict__ W2f,
        unsigned short* __restrict__ pnbf, float* __restrict__ root64) {
    __shared__ __align__(16) unsigned short As[3][128 * 32];
    __shared__ __align__(16) unsigned short Bs[3][128 * 32];

    int m0 = blockIdx.x * 128;
    int tid = threadIdx.x;
    int lane = tid & 63, wid = tid >> 6;
    int wm = wid;                       // wave owns rows wm*32 .. +31
    int quad = lane >> 4, l15 = lane & 15;
    const int csw = (quad ^ (l15 & 3)) * 8;   // swizzled 16B chunk offset

    f32x4 pacc[2][8] = {};

    stage_chunk(xbf, mean1, WcatT, m0, 0, 0, As[0], Bs[0], wid, lane);
    stage_chunk(xbf, mean1, WcatT, m0, 0, 1, As[1], Bs[1], wid, lane);

#pragma unroll 1
    for (int jj = 0; jj < 12; ++jj) {
        const int j = jj;
        f32x4 hacc[2][8] = {};
#pragma unroll
        for (int kt = 0; kt < 8; ++kt) {
            const int g = jj * 8 + kt;
            if (g == 95) wait_vm0(); else wait_vm4();
            raw_barrier();
            if (g + 2 < 96) {
                int g2 = g + 2;
                stage_chunk(xbf, mean1, WcatT, m0, g2 >> 3, g2 & 7,
                            As[g2 % 3], Bs[g2 % 3], wid, lane);
            }
            const unsigned short* Asb = As[g % 3];
            const unsigned short* Bsb = Bs[g % 3];
            bf16x8 a[2], b[8];
#pragma unroll
            for (int mi = 0; mi < 2; ++mi)
                a[mi] = *(const bf16x8*)(&Asb[(wm * 32 + mi * 16 + l15) * 32 + csw]);
#pragma unroll
            for (int ni = 0; ni < 8; ++ni)
                b[ni] = *(const bf16x8*)(&Bsb[(ni * 16 + l15) * 32 + csw]);
            __builtin_amdgcn_s_setprio(1);
#pragma unroll
            for (int mi = 0; mi < 2; ++mi)
#pragma unroll
                for (int ni = 0; ni < 8; ++ni)
                    hacc[mi][ni] = __builtin_amdgcn_mfma_f32_16x16x32_bf16(b[ni], a[mi], hacc[mi][ni], 0, 0, 0);
            __builtin_amdgcn_s_setprio(0);
        }

        // ---- layer-2 in-register: bias + ReLU + cvt_pk (R3-verified mapping)
        u32 a2w[2][4][4];                       // [mi][kk][word]
#pragma unroll
        for (int ni = 0; ni < 8; ++ni) {
            float4 bv = *(const float4*)(b1e + j * 128 + ni * 16 + quad * 4);
#pragma unroll
            for (int mi = 0; mi < 2; ++mi) {
                f32x4 h = hacc[mi][ni];
                float h0 = fmaxf(h[0] + bv.x, 0.f);
                float h1 = fmaxf(h[1] + bv.y, 0.f);
                float h2 = fmaxf(h[2] + bv.z, 0.f);
                float h3 = fmaxf(h[3] + bv.w, 0.f);
                a2w[mi][ni >> 1][(ni & 1) * 2 + 0] = cvt_pk_bf16(h0, h1);
                a2w[mi][ni >> 1][(ni & 1) * 2 + 1] = cvt_pk_bf16(h2, h3);
            }
        }
        __builtin_amdgcn_s_setprio(1);
#pragma unroll
        for (int kk = 0; kk < 4; ++kk) {
            union U { u32 w[4]; bf16x8 v; uint4 q; };
            U A2[2];
#pragma unroll
            for (int mi = 0; mi < 2; ++mi)
#pragma unroll
                for (int w = 0; w < 4; ++w) A2[mi].w[w] = a2w[mi][kk][w];
            const unsigned short* wp =
                W2f + ((size_t)(j * 4 + kk) * 128) * 32 + (size_t)quad * 8;
#pragma unroll
            for (int ni2 = 0; ni2 < 8; ++ni2) {
                U B2;
                B2.q = *(const uint4*)(wp + (size_t)(ni2 * 16 + l15) * 32);
#pragma unroll
                for (int mi = 0; mi < 2; ++mi)
                    pacc[mi][ni2] = __builtin_amdgcn_mfma_f32_16x16x32_bf16(B2.v, A2[mi].v, pacc[mi][ni2], 0, 0, 0);
            }
        }
        __builtin_amdgcn_s_setprio(0);
    }

    // ---- direct epilogue: cols 0..63 -> pnbf (bf16); cols 64..127 -> root64 --
#pragma unroll
    for (int mi = 0; mi < 2; ++mi) {
        int gr = m0 + wm * 32 + mi * 16 + l15;
        if (gr < RES0) {
#pragma unroll
            for (int ni2 = 0; ni2 < 8; ++ni2) {
                f32x4 s = pacc[mi][ni2];
                if (ni2 < 4) {
                    uint2 o;
                    o.x = (u32)f2bf(s[0]) | ((u32)f2bf(s[1]) << 16);
                    o.y = (u32)f2bf(s[2]) | ((u32)f2bf(s[3]) << 16);
                    *(uint2*)(pnbf + (size_t)gr * 64 + ni2 * 16 + quad * 4) = o;
                } else if (gr < RES1) {
                    *(f32x4*)(root64 + (size_t)gr * 64 + (ni2 - 4) * 16 + quad * 4) = s;
                }
            }
        }
    }
}

// ---------------- final: bf16 gathers, 8 edges/instr, wave/row ---------------
__global__ __launch_bounds__(256) void final_csr_kernel(
        const unsigned short* __restrict__ pnbf, const float* __restrict__ root64,
        const int* __restrict__ csr, const u32* __restrict__ off,
        const u32* __restrict__ cnt, const float* __restrict__ b2,
        float* __restrict__ out) {
    int row = blockIdx.x * 4 + (threadIdx.x >> 6);
    int lane = threadIdx.x & 63;
    if (row >= RES1) return;
    int es = lane >> 3, c8 = lane & 7;          // edge slot (0..7), 16B chunk
    u32 base = off[row], deg = cnt[row];
    float acc[8] = {};
    u32 e = 0;
    for (; e + 8 <= deg; e += 8) {
        int s = csr[base + e + es];
        u16x8 v = *(const u16x8*)(pnbf + (size_t)s * 64 + c8 * 8);
#pragma unroll
        for (int i = 0; i < 8; ++i) acc[i] += bf2f(v[i]);
    }
    if (e < deg) {
        bool valid = (e + es) < deg;
        int s = csr[base + (valid ? e + es : e)];
        u16x8 v = *(const u16x8*)(pnbf + (size_t)s * 64 + c8 * 8);
        if (valid) {
#pragma unroll
            for (int i = 0; i < 8; ++i) acc[i] += bf2f(v[i]);
        }
    }
    // reduce across the 8 edge slots (lane bits 3,4,5)
#pragma unroll
    for (int i = 0; i < 8; ++i) {
        acc[i] += __shfl_xor(acc[i], 32, 64);
        acc[i] += __shfl_xor(acc[i], 16, 64);
        acc[i] += __shfl_xor(acc[i], 8, 64);
    }
    float inv = 1.0f / fmaxf((float)deg, 1.0f);
    float v[8];
    const float* rp = root64 + (size_t)row * 64 + c8 * 8;
#pragma unroll
    for (int i = 0; i < 8; ++i) v[i] = rp[i] + acc[i] * inv + b2[c8 * 8 + i];
    float m = v[0];
#pragma unroll
    for (int i = 1; i < 8; ++i) m = fmaxf(m, v[i]);
    // values uniform across es-groups; reduce over c8 (lane bits 0,1,2)
    m = fmaxf(m, __shfl_xor(m, 1, 64));
    m = fmaxf(m, __shfl_xor(m, 2, 64));
    m = fmaxf(m, __shfl_xor(m, 4, 64));
    float s = 0.f;
#pragma unroll
    for (int i = 0; i < 8; ++i) s += expf(v[i] - m);
    s += __shfl_xor(s, 1, 64);
    s += __shfl_xor(s, 2, 64);
    s += __shfl_xor(s, 4, 64);
    if (es == 0) {
        float lg = logf(s);
        f32x4 o0, o1;
#pragma unroll
        for (int i = 0; i < 4; ++i) { o0[i] = v[i] - m - lg; o1[i] = v[i + 4] - m - lg; }
        *(f32x4*)(&out[(size_t)row * 64 + c8 * 8])     = o0;
        *(f32x4*)(&out[(size_t)row * 64 + c8 * 8 + 4]) = o1;
    }
}

extern "C" void kernel_launch(void* const* d_in, const int* in_sizes, int n_in,
                              void* d_out, int out_size, void* d_ws, size_t ws_size,
                              hipStream_t stream) {
    const float* x   = (const float*)d_in[0];
    const float* W1r = (const float*)d_in[1];
    const float* W1n = (const float*)d_in[2];
    const float* b1  = (const float*)d_in[3];
    const float* W2r = (const float*)d_in[4];
    const float* W2n = (const float*)d_in[5];
    const float* b2  = (const float*)d_in[6];
    const int* es0 = (const int*)d_in[7];
    const int* et0 = (const int*)d_in[8];
    const int* es1 = (const int*)d_in[9];
    const int* et1 = (const int*)d_in[10];
    float* out = (float*)d_out;

    char* ws = (char*)d_ws;
    size_t off_ = 0;
    auto alloc = [&](size_t bytes) {
        void* ptr = ws + off_;
        off_ = (off_ + bytes + 255) & ~(size_t)255;
        return ptr;
    };
    u64* bkt1  = (u64*)alloc((size_t)E0N * 8);        // 12.8 MB
    u64* bkt2  = (u64*)alloc((size_t)E1N * 8);        //  4.0 MB
    int* csr1  = (int*)alloc((size_t)E0N * 4);        //  6.4 MB
    u32* H1    = (u32*)alloc((size_t)NCH0 * NB0 * 4);
    u32* base1 = (u32*)alloc((size_t)NCH0 * NB0 * 4);
    u32* H2    = (u32*)alloc((size_t)NCH1 * NB1 * 4);
    u32* base2 = (u32*)alloc((size_t)NCH1 * NB1 * 4);
    u32* Bsum1 = (u32*)alloc((size_t)NB0 * 4);
    u32* Bsum2 = (u32*)alloc((size_t)NB1 * 4);
    u32* boff1 = (u32*)alloc((size_t)NB0 * 4);
    u32* boff2 = (u32*)alloc((size_t)NB1 * 4);
    u32* off1  = (u32*)alloc((size_t)RES0 * 4);
    u32* cnt1  = (u32*)alloc((size_t)RES0 * 4);
    int* csr2  = (int*)alloc((size_t)E1N * 4);
    u32* off2  = (u32*)alloc((size_t)RES1 * 4);
    u32* cnt2  = (u32*)alloc((size_t)RES1 * 4);
    unsigned short* xbf    = (unsigned short*)alloc((size_t)NSRC * NF * 2);
    unsigned short* mean1  = (unsigned short*)alloc((size_t)(RES0 + 128) * NF * 2);
    unsigned short* WcatT  = (unsigned short*)alloc((size_t)NHIDP * 256 * 2);
    unsigned short* W2f    = (unsigned short*)alloc((size_t)128 * NHIDP * 2);
    float*          b1e    = (float*)alloc((size_t)NHIDP * 4);
    unsigned short* pnbf   = (unsigned short*)alloc((size_t)RES0 * 64 * 2);
    float*          root64 = (float*)alloc((size_t)RES1 * 64 * 4);

    setup_kernel<<<PREP_BLOCKS + COPYX_BLOCKS, 256, 0, stream>>>(
        x, xbf, W1r, W1n, b1, W2r, W2n, WcatT, W2f, b1e);

    p1a_both_kernel<<<NCH0 + NCH1, 256, 0, stream>>>(et0, et1, H1, H2);
    bscan_both_kernel<<<NB0 + NB1, 512, 0, stream>>>(H1, base1, Bsum1, H2, base2, Bsum2);
    boff_kernel<<<2, 256, 0, stream>>>(Bsum1, boff1, NB0, Bsum2, boff2, NB1);
    p1b_both_kernel<<<NCH0 + NCH1, 256, 0, stream>>>(
        es0, et0, base1, boff1, bkt1, es1, et1, base2, boff2, bkt2);
    p2_both_kernel<<<NB0 + NB1, 1024, 0, stream>>>(
        bkt1, boff1, csr1, off1, cnt1, bkt2, boff2, csr2, off2, cnt2);

    agg1_csr_kernel<<<(RES0 + 3) / 4, 256, 0, stream>>>(
        xbf, csr1, off1, cnt1, mean1);

    fused_gemm_kernel<<<(RES0 + 127) / 128, 256, 0, stream>>>(
        xbf, mean1, WcatT, b1e, W2f, pnbf, root64);

    final_csr_kernel<<<(RES1 + 3) / 4, 256, 0, stream>>>(
        pnbf, root64, csr2, off2, cnt2, b2, out);
}

// Round 6
// 434.630 us; speedup vs baseline: 1.0088x; 1.0088x over previous
//
#include <hip/hip_runtime.h>
#include <hip/hip_bf16.h>
#include <cstdint>
#include <cstddef>

// Problem constants (from reference)
#define NSRC   200000
#define NF     128
#define NHID   1500
#define NHIDP  1536     // padded hidden dim (multiple of 128)
#define NCLS   64
#define E0N    1600000
#define E1N    500000
#define RES0   50000
#define RES1   10000

// CSR bucket-sort parameters
#define CH     4096                       // edges per chunk
#define NCH0   ((E0N + CH - 1) / CH)      // 391
#define NCH1   ((E1N + CH - 1) / CH)      // 123
#define NB0    ((RES0 + 255) / 256)      // 196 buckets of 256 targets
#define NB1    ((RES1 + 255) / 256)      // 40

#define PREP_BLOCKS  ((256 * NHIDP + 128 * NHIDP + NHIDP + 255) / 256)   // 2310
#define COPYX_BLOCKS ((NSRC * NF) / (256 * 8))                           // 12500

typedef __bf16 bf16x8 __attribute__((ext_vector_type(8)));
typedef float  f32x4  __attribute__((ext_vector_type(4)));
typedef unsigned short u16x8 __attribute__((ext_vector_type(8)));
typedef unsigned int u32;
typedef unsigned long long u64;

__device__ __forceinline__ unsigned short f2bf(float f) {
    union { float f; unsigned u; } v; v.f = f;
    unsigned r = v.u + 0x7fffu + ((v.u >> 16) & 1u);   // RNE
    return (unsigned short)(r >> 16);
}
__device__ __forceinline__ float bf2f(unsigned short b) {
    union { u32 u; float f; } v; v.u = ((u32)b) << 16;
    return v.f;
}

// pack 2 f32 -> 2 bf16 in one u32, inline asm (no builtin on gfx950)
__device__ __forceinline__ u32 cvt_pk_bf16(float lo, float hi) {
    u32 r;
    asm("v_cvt_pk_bf16_f32 %0, %1, %2" : "=v"(r) : "v"(lo), "v"(hi));
    return r;
}

// async 16B global -> LDS DMA (dest = wave-uniform lds base + lane*16)
__device__ __forceinline__ void lds_dma16(const void* g, void* lds) {
    __builtin_amdgcn_global_load_lds(
        (const __attribute__((address_space(1))) unsigned int*)g,
        (__attribute__((address_space(3))) unsigned int*)lds, 16, 0, 0);
}

// raw barrier/wait primitives: s_barrier WITHOUT the compiler's vmcnt(0) drain.
__device__ __forceinline__ void raw_barrier() {
    __asm__ volatile("s_barrier" ::: "memory");
}
__device__ __forceinline__ void wait_vm8() {
    __asm__ volatile("s_waitcnt vmcnt(8)" ::: "memory");
}
__device__ __forceinline__ void wait_vm4() {
    __asm__ volatile("s_waitcnt vmcnt(4)" ::: "memory");
}
__device__ __forceinline__ void wait_vm0() {
    __asm__ volatile("s_waitcnt vmcnt(0)" ::: "memory");
}

// ---------------- CSR phase 1a body (shared by setup mega-kernel) ------------
__device__ __forceinline__ void p1a_body(const int* __restrict__ tgt, int n,
                                         int nb, u32* __restrict__ H, int c) {
    __shared__ u32 lhist[256];
    int tid = threadIdx.x;
    lhist[tid] = 0;
    __syncthreads();
#pragma unroll
    for (int it = 0; it < CH / 256; ++it) {
        int i = c * CH + it * 256 + tid;
        if (i < n) atomicAdd(&lhist[((u32)tgt[i]) >> 8], 1u);
    }
    __syncthreads();
    if (tid < nb) H[c * nb + tid] = lhist[tid];
}

// ---------------- setup: weight prep + x->bf16 copy + p1a histograms --------
// W2f layout (MFMA-fragment order): for output col n, k = j*128 + kk*32 +
// hi*16 + qd*4 + e  ->  W2f[((j*4+kk)*128 + n)*32 + qd*8 + hi*4 + e].
__global__ __launch_bounds__(256) void setup_kernel(
        const float* __restrict__ x, unsigned short* __restrict__ xbf,
        const float* __restrict__ W1r, const float* __restrict__ W1n,
        const float* __restrict__ b1,
        const float* __restrict__ W2r, const float* __restrict__ W2n,
        unsigned short* __restrict__ WcatT, unsigned short* __restrict__ W2f,
        float* __restrict__ b1e,
        const int* __restrict__ t0, const int* __restrict__ t1,
        u32* __restrict__ H1, u32* __restrict__ H2) {
    int bid = blockIdx.x;
    if (bid < PREP_BLOCKS) {
        int id = bid * 256 + threadIdx.x;
        if (id < 256 * NHIDP) {
            int n = id >> 8, k = id & 255;
            float v = 0.f;
            if (n < NHID) v = (k < NF) ? W1r[k * NHID + n] : W1n[(k - NF) * NHID + n];
            WcatT[n * 256 + k] = f2bf(v);
        } else {
            int id2 = id - 256 * NHIDP;
            if (id2 < 128 * NHIDP) {
                int n = id2 / NHIDP, k = id2 % NHIDP;
                float v = 0.f;
                if (k < NHID) v = (n < 64) ? W2n[k * 64 + n] : W2r[k * 64 + (n - 64)];
                int j = k >> 7, w = k & 127;
                int kk = w >> 5, r = w & 31;
                int hi = r >> 4, qd = (r >> 2) & 3, e = r & 3;
                W2f[(((size_t)(j * 4 + kk) * 128 + n) * 32) + qd * 8 + hi * 4 + e] = f2bf(v);
            } else {
                int c = id2 - 128 * NHIDP;
                if (c < NHIDP) b1e[c] = (c < NHID) ? b1[c] : 0.f;
            }
        }
    } else if (bid < PREP_BLOCKS + COPYX_BLOCKS) {
        size_t i = ((size_t)(bid - PREP_BLOCKS) * 256 + threadIdx.x) * 8;
        const float4* s = (const float4*)(x + i);
        float4 a = s[0], b = s[1];
        u16x8 o;
        o[0] = f2bf(a.x); o[1] = f2bf(a.y); o[2] = f2bf(a.z); o[3] = f2bf(a.w);
        o[4] = f2bf(b.x); o[5] = f2bf(b.y); o[6] = f2bf(b.z); o[7] = f2bf(b.w);
        *(u16x8*)(xbf + i) = o;
    } else {
        int c = bid - (PREP_BLOCKS + COPYX_BLOCKS);
        if (c < NCH0) p1a_body(t0, E0N, NB0, H1, c);
        else          p1a_body(t1, E1N, NB1, H2, c - NCH0);
    }
}

// ---------------- bscan: per-bucket exclusive scan over chunks + totals ------
__device__ __forceinline__ void bscan_body(const u32* __restrict__ H,
                                           int nch, int nb, int b,
                                           u32* __restrict__ base_rel,
                                           u32* __restrict__ Bsum) {
    __shared__ u32 part[512];
    int t = threadIdx.x;
    part[t] = (t < nch) ? H[t * nb + b] : 0u;
    __syncthreads();
    for (int d = 1; d < 512; d <<= 1) {
        u32 v = part[t];
        u32 add = (t >= d) ? part[t - d] : 0u;
        __syncthreads();
        part[t] = v + add;
        __syncthreads();
    }
    if (t < nch) base_rel[t * nb + b] = (t == 0) ? 0u : part[t - 1];
    if (t == 0) Bsum[b] = part[nch - 1];
}

__global__ __launch_bounds__(512) void bscan_both_kernel(
        const u32* __restrict__ H1, u32* __restrict__ base1, u32* __restrict__ Bsum1,
        const u32* __restrict__ H2, u32* __restrict__ base2, u32* __restrict__ Bsum2) {
    int b = blockIdx.x;
    if (b < NB0) bscan_body(H1, NCH0, NB0, b, base1, Bsum1);
    else         bscan_body(H2, NCH1, NB1, b - NB0, base2, Bsum2);
}

// ---------------- boff: exclusive scan over bucket totals (both graphs) ------
__global__ __launch_bounds__(256) void boff_kernel(const u32* __restrict__ Bsum1,
                                                   u32* __restrict__ boff1, int nb1,
                                                   const u32* __restrict__ Bsum2,
                                                   u32* __restrict__ boff2, int nb2) {
    const u32* B = blockIdx.x ? Bsum2 : Bsum1;
    u32* O = blockIdx.x ? boff2 : boff1;
    int nb = blockIdx.x ? nb2 : nb1;
    __shared__ u32 part[256];
    int t = threadIdx.x;
    part[t] = (t < nb) ? B[t] : 0u;
    __syncthreads();
    for (int d = 1; d < 256; d <<= 1) {
        u32 v = part[t];
        u32 add = (t >= d) ? part[t - d] : 0u;
        __syncthreads();
        part[t] = v + add;
        __syncthreads();
    }
    if (t < nb) O[t] = (t == 0) ? 0u : part[t - 1];
}

// ---------------- phase 1b: bucket-grouped scatter of (tgt,src) pairs --------
__device__ __forceinline__ void p1b_body(const int* __restrict__ src,
                                         const int* __restrict__ tgt, int n,
                                         int nb, const u32* __restrict__ base_rel,
                                         const u32* __restrict__ boff,
                                         u64* __restrict__ bucketed, int c) {
    __shared__ u32 lcur[256];
    __shared__ u32 lbase[256];
    int tid = threadIdx.x;
    lcur[tid] = 0;
    if (tid < nb) lbase[tid] = base_rel[c * nb + tid] + boff[tid];
    __syncthreads();
#pragma unroll
    for (int it = 0; it < CH / 256; ++it) {
        int i = c * CH + it * 256 + tid;
        if (i < n) {
            u32 t = (u32)tgt[i];
            u32 s = (u32)src[i];
            u32 b = t >> 8;
            u32 r = atomicAdd(&lcur[b], 1u);
            bucketed[lbase[b] + r] = ((u64)t << 32) | (u64)s;
        }
    }
}

__global__ __launch_bounds__(256) void p1b_both_kernel(
        const int* __restrict__ s0, const int* __restrict__ t0,
        const u32* __restrict__ base1, const u32* __restrict__ boff1,
        u64* __restrict__ bkt1,
        const int* __restrict__ s1, const int* __restrict__ t1,
        const u32* __restrict__ base2, const u32* __restrict__ boff2,
        u64* __restrict__ bkt2) {
    int b = blockIdx.x;
    if (b < NCH0) p1b_body(s0, t0, E0N, NB0, base1, boff1, bkt1, b);
    else          p1b_body(s1, t1, E1N, NB1, base2, boff2, bkt2, b - NCH0);
}

// ---------------- phase 2: per-bucket sort -> CSR + per-target off/cnt -------
__device__ __forceinline__ void p2_body(const u64* __restrict__ bucketed,
                                        const u32* __restrict__ boff,
                                        int nb, int res, int etot,
                                        int* __restrict__ csr,
                                        u32* __restrict__ off_out,
                                        u32* __restrict__ cnt_out, int b) {
    __shared__ u32 lhist[256];
    __shared__ u32 part[256];
    __shared__ u32 cur[256];
    int tid = threadIdx.x;
    u32 start = boff[b];
    u32 end = (b == nb - 1) ? (u32)etot : boff[b + 1];
    u32 count = end - start;
    if (tid < 256) lhist[tid] = 0;
    __syncthreads();
    for (u32 i = tid; i < count; i += 1024) {
        u32 t = (u32)(bucketed[start + i] >> 32);
        atomicAdd(&lhist[t & 255u], 1u);
    }
    __syncthreads();
    if (tid < 256) part[tid] = lhist[tid];
    __syncthreads();
    for (int d = 1; d < 256; d <<= 1) {
        u32 v = (tid < 256) ? part[tid] : 0u;
        u32 add = (tid >= d && tid < 256) ? part[tid - d] : 0u;
        __syncthreads();
        if (tid < 256) part[tid] = v + add;
        __syncthreads();
    }
    if (tid < 256) {
        u32 excl = (tid == 0) ? 0u : part[tid - 1];
        cur[tid] = excl;
        int tg = (b << 8) + tid;
        if (tg < res) {
            off_out[tg] = start + excl;
            cnt_out[tg] = lhist[tid];
        }
    }
    __syncthreads();
    for (u32 i = tid; i < count; i += 1024) {
        u64 pr = bucketed[start + i];
        u32 lt = ((u32)(pr >> 32)) & 255u;
        u32 r = atomicAdd(&cur[lt], 1u);
        csr[start + r] = (int)(u32)pr;
    }
}

__global__ __launch_bounds__(1024) void p2_both_kernel(
        const u64* __restrict__ bkt1, const u32* __restrict__ boff1,
        int* __restrict__ csr1, u32* __restrict__ off1, u32* __restrict__ cnt1,
        const u64* __restrict__ bkt2, const u32* __restrict__ boff2,
        int* __restrict__ csr2, u32* __restrict__ off2, u32* __restrict__ cnt2) {
    int b = blockIdx.x;
    if (b < NB0) p2_body(bkt1, boff1, NB0, RES0, E0N, csr1, off1, cnt1, b);
    else         p2_body(bkt2, boff2, NB1, RES1, E1N, csr2, off2, cnt2, b - NB0);
}

// ---------------- layer-1 mean: 1 wave/row, 16 lanes/row, 16 edges in flight -
__global__ __launch_bounds__(256) void agg1_csr_kernel(
        const unsigned short* __restrict__ xbf, const int* __restrict__ csr,
        const u32* __restrict__ off, const u32* __restrict__ cnt,
        unsigned short* __restrict__ mean1) {
    int row = blockIdx.x * 4 + (threadIdx.x >> 6);
    int lane = threadIdx.x & 63;
    if (row >= RES0) return;
    int q = lane >> 4, c16 = lane & 15;            // edge slot, 16B chunk
    u32 base = off[row], deg = cnt[row];
    float acc[8] = {};
    u32 e = 0;
    // 16 edges in flight (4 index loads + 4 gathers/iter)
    for (; e + 16 <= deg; e += 16) {
        int s0 = csr[base + e + q];
        int s1 = csr[base + e + 4 + q];
        int s2 = csr[base + e + 8 + q];
        int s3 = csr[base + e + 12 + q];
        u16x8 v0 = *(const u16x8*)(xbf + (size_t)s0 * NF + c16 * 8);
        u16x8 v1 = *(const u16x8*)(xbf + (size_t)s1 * NF + c16 * 8);
        u16x8 v2 = *(const u16x8*)(xbf + (size_t)s2 * NF + c16 * 8);
        u16x8 v3 = *(const u16x8*)(xbf + (size_t)s3 * NF + c16 * 8);
#pragma unroll
        for (int i = 0; i < 8; ++i)
            acc[i] += (bf2f(v0[i]) + bf2f(v1[i])) + (bf2f(v2[i]) + bf2f(v3[i]));
    }
    for (; e + 8 <= deg; e += 8) {
        int s0 = csr[base + e + q];
        int s1 = csr[base + e + 4 + q];
        u16x8 v0 = *(const u16x8*)(xbf + (size_t)s0 * NF + c16 * 8);
        u16x8 v1 = *(const u16x8*)(xbf + (size_t)s1 * NF + c16 * 8);
#pragma unroll
        for (int i = 0; i < 8; ++i) acc[i] += bf2f(v0[i]) + bf2f(v1[i]);
    }
    for (; e + 4 <= deg; e += 4) {
        int s0 = csr[base + e + q];
        u16x8 v0 = *(const u16x8*)(xbf + (size_t)s0 * NF + c16 * 8);
#pragma unroll
        for (int i = 0; i < 8; ++i) acc[i] += bf2f(v0[i]);
    }
    if (e < deg) {
        bool valid = (e + q) < deg;
        int s0 = csr[base + (valid ? e + q : e)];
        u16x8 v0 = *(const u16x8*)(xbf + (size_t)s0 * NF + c16 * 8);
        if (valid) {
#pragma unroll
            for (int i = 0; i < 8; ++i) acc[i] += bf2f(v0[i]);
        }
    }
    // reduce across the 4 edge slots (lane bits 4,5)
#pragma unroll
    for (int i = 0; i < 8; ++i) {
        acc[i] += __shfl_xor(acc[i], 32, 64);
        acc[i] += __shfl_xor(acc[i], 16, 64);
    }
    if (q == 0) {
        float inv = 1.0f / fmaxf((float)deg, 1.0f);
        u16x8 o;
#pragma unroll
        for (int i = 0; i < 8; ++i) o[i] = f2bf(acc[i] * inv);
        *(u16x8*)(mean1 + (size_t)row * NF + c16 * 8) = o;
    }
}

// ---------------- fused GEMM staging helper (XOR-swizzled source) ------------
__device__ __forceinline__ void stage_chunk(
        const unsigned short* __restrict__ xbf, const unsigned short* __restrict__ mean1,
        const unsigned short* __restrict__ WcatT, int m0, int j, int kt,
        unsigned short* As, unsigned short* Bs, int wid, int lane) {
    int ksel = kt * 32;
    const unsigned short* srcA = (ksel < 128)
        ? xbf + (size_t)m0 * NF + ksel
        : mean1 + (size_t)m0 * NF + (ksel - 128);
#pragma unroll
    for (int ci = 0; ci < 2; ++ci) {
        int cb = ci * 256 + wid * 64;
        int chunk = cb + lane;
        int n = chunk >> 2, kc = (chunk & 3) ^ (n & 3);
        lds_dma16(srcA + (size_t)n * NF + kc * 8, &As[cb * 8]);
    }
    const unsigned short* srcB = WcatT + (size_t)(j * 128) * 256 + ksel;
#pragma unroll
    for (int ci = 0; ci < 2; ++ci) {
        int cb = ci * 256 + wid * 64;
        int chunk = cb + lane;
        int n = chunk >> 2, kc = (chunk & 3) ^ (n & 3);
        lds_dma16(srcB + (size_t)n * 256 + kc * 8, &Bs[cb * 8]);
    }
}

// ---------------- fused GEMM v6: depth-3 prefetch (4-buffer ring) ------------
// 128-row tile, 4 waves of 32 rows x full 128 cols, 16 MFMA/phase, in-register
// layer-2 (R3/R5-verified slot->k mapping), direct pnbf/root64 epilogue.
// NEW: 4 staging buffers, issue depth 3 (12 DMAs in flight per wave vs 8) to
// raise global_load_lds throughput — the R5 post-mortem's latency×depth bound.
// LDS 64 KB -> 2 blocks/CU.
__global__ __launch_bounds__(256, 2) void fused_gemm_kernel(
        const unsigned short* __restrict__ xbf, const unsigned short* __restrict__ mean1,
        const unsigned short* __restrict__ WcatT, const float* __restrict__ b1e,
        const unsigned short* __restrict__ W2f,
        unsigned short* __restrict__ pnbf, float* __restrict__ root64) {
    __shared__ __align__(16) unsigned short As[4][128 * 32];
    __shared__ __align__(16) unsigned short Bs[4][128 * 32];

    int m0 = blockIdx.x * 128;
    int tid = threadIdx.x;
    int lane = tid & 63, wid = tid >> 6;
    int wm = wid;                       // wave owns rows wm*32 .. +31
    int quad = lane >> 4, l15 = lane & 15;
    const int csw = (quad ^ (l15 & 3)) * 8;   // swizzled 16B chunk offset

    f32x4 pacc[2][8] = {};

    stage_chunk(xbf, mean1, WcatT, m0, 0, 0, As[0], Bs[0], wid, lane);
    stage_chunk(xbf, mean1, WcatT, m0, 0, 1, As[1], Bs[1], wid, lane);
    stage_chunk(xbf, mean1, WcatT, m0, 0, 2, As[2], Bs[2], wid, lane);

#pragma unroll 1
    for (int jj = 0; jj < 12; ++jj) {
        const int j = jj;
        f32x4 hacc[2][8] = {};
#pragma unroll
        for (int kt = 0; kt < 8; ++kt) {
            const int g = jj * 8 + kt;
            if (g <= 93) wait_vm8();
            else if (g == 94) wait_vm4();
            else wait_vm0();
            raw_barrier();
            if (g + 3 < 96) {
                int g3 = g + 3;
                stage_chunk(xbf, mean1, WcatT, m0, g3 >> 3, g3 & 7,
                            As[g3 & 3], Bs[g3 & 3], wid, lane);
            }
            const unsigned short* Asb = As[g & 3];
            const unsigned short* Bsb = Bs[g & 3];
            bf16x8 a[2], b[8];
#pragma unroll
            for (int mi = 0; mi < 2; ++mi)
                a[mi] = *(const bf16x8*)(&Asb[(wm * 32 + mi * 16 + l15) * 32 + csw]);
#pragma unroll
            for (int ni = 0; ni < 8; ++ni)
                b[ni] = *(const bf16x8*)(&Bsb[(ni * 16 + l15) * 32 + csw]);
            __builtin_amdgcn_s_setprio(1);
#pragma unroll
            for (int mi = 0; mi < 2; ++mi)
#pragma unroll
                for (int ni = 0; ni < 8; ++ni)
                    hacc[mi][ni] = __builtin_amdgcn_mfma_f32_16x16x32_bf16(b[ni], a[mi], hacc[mi][ni], 0, 0, 0);
            __builtin_amdgcn_s_setprio(0);
        }

        // ---- layer-2 in-register: bias + ReLU + cvt_pk (verified mapping)
        u32 a2w[2][4][4];                       // [mi][kk][word]
#pragma unroll
        for (int ni = 0; ni < 8; ++ni) {
            float4 bv = *(const float4*)(b1e + j * 128 + ni * 16 + quad * 4);
#pragma unroll
            for (int mi = 0; mi < 2; ++mi) {
                f32x4 h = hacc[mi][ni];
                float h0 = fmaxf(h[0] + bv.x, 0.f);
                float h1 = fmaxf(h[1] + bv.y, 0.f);
                float h2 = fmaxf(h[2] + bv.z, 0.f);
                float h3 = fmaxf(h[3] + bv.w, 0.f);
                a2w[mi][ni >> 1][(ni & 1) * 2 + 0] = cvt_pk_bf16(h0, h1);
                a2w[mi][ni >> 1][(ni & 1) * 2 + 1] = cvt_pk_bf16(h2, h3);
            }
        }
        __builtin_amdgcn_s_setprio(1);
#pragma unroll
        for (int kk = 0; kk < 4; ++kk) {
            union U { u32 w[4]; bf16x8 v; uint4 q; };
            U A2[2];
#pragma unroll
            for (int mi = 0; mi < 2; ++mi)
#pragma unroll
                for (int w = 0; w < 4; ++w) A2[mi].w[w] = a2w[mi][kk][w];
            const unsigned short* wp =
                W2f + ((size_t)(j * 4 + kk) * 128) * 32 + (size_t)quad * 8;
#pragma unroll
            for (int ni2 = 0; ni2 < 8; ++ni2) {
                U B2;
                B2.q = *(const uint4*)(wp + (size_t)(ni2 * 16 + l15) * 32);
#pragma unroll
                for (int mi = 0; mi < 2; ++mi)
                    pacc[mi][ni2] = __builtin_amdgcn_mfma_f32_16x16x32_bf16(B2.v, A2[mi].v, pacc[mi][ni2], 0, 0, 0);
            }
        }
        __builtin_amdgcn_s_setprio(0);
    }

    // ---- direct epilogue: cols 0..63 -> pnbf (bf16); cols 64..127 -> root64 --
#pragma unroll
    for (int mi = 0; mi < 2; ++mi) {
        int gr = m0 + wm * 32 + mi * 16 + l15;
        if (gr < RES0) {
#pragma unroll
            for (int ni2 = 0; ni2 < 8; ++ni2) {
                f32x4 s = pacc[mi][ni2];
                if (ni2 < 4) {
                    uint2 o;
                    o.x = (u32)f2bf(s[0]) | ((u32)f2bf(s[1]) << 16);
                    o.y = (u32)f2bf(s[2]) | ((u32)f2bf(s[3]) << 16);
                    *(uint2*)(pnbf + (size_t)gr * 64 + ni2 * 16 + quad * 4) = o;
                } else if (gr < RES1) {
                    *(f32x4*)(root64 + (size_t)gr * 64 + (ni2 - 4) * 16 + quad * 4) = s;
                }
            }
        }
    }
}

// ---------------- final: bf16 gathers, 8 edges/instr, wave/row ---------------
__global__ __launch_bounds__(256) void final_csr_kernel(
        const unsigned short* __restrict__ pnbf, const float* __restrict__ root64,
        const int* __restrict__ csr, const u32* __restrict__ off,
        const u32* __restrict__ cnt, const float* __restrict__ b2,
        float* __restrict__ out) {
    int row = blockIdx.x * 4 + (threadIdx.x >> 6);
    int lane = threadIdx.x & 63;
    if (row >= RES1) return;
    int es = lane >> 3, c8 = lane & 7;          // edge slot (0..7), 16B chunk
    u32 base = off[row], deg = cnt[row];
    float acc[8] = {};
    u32 e = 0;
    for (; e + 8 <= deg; e += 8) {
        int s = csr[base + e + es];
        u16x8 v = *(const u16x8*)(pnbf + (size_t)s * 64 + c8 * 8);
#pragma unroll
        for (int i = 0; i < 8; ++i) acc[i] += bf2f(v[i]);
    }
    if (e < deg) {
        bool valid = (e + es) < deg;
        int s = csr[base + (valid ? e + es : e)];
        u16x8 v = *(const u16x8*)(pnbf + (size_t)s * 64 + c8 * 8);
        if (valid) {
#pragma unroll
            for (int i = 0; i < 8; ++i) acc[i] += bf2f(v[i]);
        }
    }
    // reduce across the 8 edge slots (lane bits 3,4,5)
#pragma unroll
    for (int i = 0; i < 8; ++i) {
        acc[i] += __shfl_xor(acc[i], 32, 64);
        acc[i] += __shfl_xor(acc[i], 16, 64);
        acc[i] += __shfl_xor(acc[i], 8, 64);
    }
    float inv = 1.0f / fmaxf((float)deg, 1.0f);
    float v[8];
    const float* rp = root64 + (size_t)row * 64 + c8 * 8;
#pragma unroll
    for (int i = 0; i < 8; ++i) v[i] = rp[i] + acc[i] * inv + b2[c8 * 8 + i];
    float m = v[0];
#pragma unroll
    for (int i = 1; i < 8; ++i) m = fmaxf(m, v[i]);
    // values uniform across es-groups; reduce over c8 (lane bits 0,1,2)
    m = fmaxf(m, __shfl_xor(m, 1, 64));
    m = fmaxf(m, __shfl_xor(m, 2, 64));
    m = fmaxf(m, __shfl_xor(m, 4, 64));
    float s = 0.f;
#pragma unroll
    for (int i = 0; i < 8; ++i) s += expf(v[i] - m);
    s += __shfl_xor(s, 1, 64);
    s += __shfl_xor(s, 2, 64);
    s += __shfl_xor(s, 4, 64);
    if (es == 0) {
        float lg = logf(s);
        f32x4 o0, o1;
#pragma unroll
        for (int i = 0; i < 4; ++i) { o0[i] = v[i] - m - lg; o1[i] = v[i + 4] - m - lg; }
        *(f32x4*)(&out[(size_t)row * 64 + c8 * 8])     = o0;
        *(f32x4*)(&out[(size_t)row * 64 + c8 * 8 + 4]) = o1;
    }
}

extern "C" void kernel_launch(void* const* d_in, const int* in_sizes, int n_in,
                              void* d_out, int out_size, void* d_ws, size_t ws_size,
                              hipStream_t stream) {
    const float* x   = (const float*)d_in[0];
    const float* W1r = (const float*)d_in[1];
    const float* W1n = (const float*)d_in[2];
    const float* b1  = (const float*)d_in[3];
    const float* W2r = (const float*)d_in[4];
    const float* W2n = (const float*)d_in[5];
    const float* b2  = (const float*)d_in[6];
    const int* es0 = (const int*)d_in[7];
    const int* et0 = (const int*)d_in[8];
    const int* es1 = (const int*)d_in[9];
    const int* et1 = (const int*)d_in[10];
    float* out = (float*)d_out;

    char* ws = (char*)d_ws;
    size_t off_ = 0;
    auto alloc = [&](size_t bytes) {
        void* ptr = ws + off_;
        off_ = (off_ + bytes + 255) & ~(size_t)255;
        return ptr;
    };
    u64* bkt1  = (u64*)alloc((size_t)E0N * 8);        // 12.8 MB
    u64* bkt2  = (u64*)alloc((size_t)E1N * 8);        //  4.0 MB
    int* csr1  = (int*)alloc((size_t)E0N * 4);        //  6.4 MB
    u32* H1    = (u32*)alloc((size_t)NCH0 * NB0 * 4);
    u32* base1 = (u32*)alloc((size_t)NCH0 * NB0 * 4);
    u32* H2    = (u32*)alloc((size_t)NCH1 * NB1 * 4);
    u32* base2 = (u32*)alloc((size_t)NCH1 * NB1 * 4);
    u32* Bsum1 = (u32*)alloc((size_t)NB0 * 4);
    u32* Bsum2 = (u32*)alloc((size_t)NB1 * 4);
    u32* boff1 = (u32*)alloc((size_t)NB0 * 4);
    u32* boff2 = (u32*)alloc((size_t)NB1 * 4);
    u32* off1  = (u32*)alloc((size_t)RES0 * 4);
    u32* cnt1  = (u32*)alloc((size_t)RES0 * 4);
    int* csr2  = (int*)alloc((size_t)E1N * 4);
    u32* off2  = (u32*)alloc((size_t)RES1 * 4);
    u32* cnt2  = (u32*)alloc((size_t)RES1 * 4);
    unsigned short* xbf    = (unsigned short*)alloc((size_t)NSRC * NF * 2);
    unsigned short* mean1  = (unsigned short*)alloc((size_t)(RES0 + 128) * NF * 2);
    unsigned short* WcatT  = (unsigned short*)alloc((size_t)NHIDP * 256 * 2);
    unsigned short* W2f    = (unsigned short*)alloc((size_t)128 * NHIDP * 2);
    float*          b1e    = (float*)alloc((size_t)NHIDP * 4);
    unsigned short* pnbf   = (unsigned short*)alloc((size_t)RES0 * 64 * 2);
    float*          root64 = (float*)alloc((size_t)RES1 * 64 * 4);

    setup_kernel<<<PREP_BLOCKS + COPYX_BLOCKS + NCH0 + NCH1, 256, 0, stream>>>(
        x, xbf, W1r, W1n, b1, W2r, W2n, WcatT, W2f, b1e, et0, et1, H1, H2);

    bscan_both_kernel<<<NB0 + NB1, 512, 0, stream>>>(H1, base1, Bsum1, H2, base2, Bsum2);
    boff_kernel<<<2, 256, 0, stream>>>(Bsum1, boff1, NB0, Bsum2, boff2, NB1);
    p1b_both_kernel<<<NCH0 + NCH1, 256, 0, stream>>>(
        es0, et0, base1, boff1, bkt1, es1, et1, base2, boff2, bkt2);
    p2_both_kernel<<<NB0 + NB1, 1024, 0, stream>>>(
        bkt1, boff1, csr1, off1, cnt1, bkt2, boff2, csr2, off2, cnt2);

    agg1_csr_kernel<<<(RES0 + 3) / 4, 256, 0, stream>>>(
        xbf, csr1, off1, cnt1, mean1);

    fused_gemm_kernel<<<(RES0 + 127) / 128, 256, 0, stream>>>(
        xbf, mean1, WcatT, b1e, W2f, pnbf, root64);

    final_csr_kernel<<<(RES1 + 3) / 4, 256, 0, stream>>>(
        pnbf, root64, csr2, off2, cnt2, b2, out);
}